// Round 3
// baseline (385.790 us; speedup 1.0000x reference)
//
#include <hip/hip_runtime.h>
#include <stdint.h>

// MHA fused: qkv-proj (ring-3 pipelined bf16 MFMA GEMM) -> causal flash attn -> out-proj
// B=2, S=2048, H=2048, heads=16, D=128.

using bf16x8 = __attribute__((ext_vector_type(8))) __bf16;
using f32x4  = __attribute__((ext_vector_type(4))) float;

#define S_LEN 2048
#define HID   2048
#define NHEAD 16
#define DHEAD 128
#define KDIM  2048
// 1/sqrt(128) * log2(e): attention softmax runs in exp2 domain
#define QSCALE_L2E (0.08838834764831845f * 1.4426950408889634f)

__device__ __forceinline__ unsigned short f2bf(float f) {
  union { float f; unsigned int u; } c; c.f = f;
  unsigned int u = c.u;
  return (unsigned short)((u + 0x7FFFu + ((u >> 16) & 1u)) >> 16);  // RNE
}

__device__ __forceinline__ unsigned int pkbf(float a, float b) {
  union { __bf16 h[2]; unsigned int u; } x;
  x.h[0] = (__bf16)a; x.h[1] = (__bf16)b;
  return x.u;
}

__device__ __forceinline__ void gload_lds16(const void* g, void* l) {
  __builtin_amdgcn_global_load_lds(
      (const __attribute__((address_space(1))) unsigned int*)g,
      (__attribute__((address_space(3))) unsigned int*)l, 16, 0, 0);
}

__device__ __forceinline__ f32x4 mfma16(bf16x8 a, bf16x8 b, f32x4 c) {
  return __builtin_amdgcn_mfma_f32_16x16x32_bf16(a, b, c, 0, 0, 0);
}

__device__ __forceinline__ float hmax4(f32x4 v) {
  return fmaxf(fmaxf(v[0], v[1]), fmaxf(v[2], v[3]));
}

template<int N> __device__ __forceinline__ void waitvm() {
  if constexpr (N == 3)      asm volatile("s_waitcnt vmcnt(3)" ::: "memory");
  else if constexpr (N == 4) asm volatile("s_waitcnt vmcnt(4)" ::: "memory");
  else                       asm volatile("s_waitcnt vmcnt(0)" ::: "memory");
}

__global__ void cvt_bf16(const float* __restrict__ in, unsigned short* __restrict__ out, int n) {
  const int n4 = n >> 2;
  const int stride = gridDim.x * blockDim.x;
  for (int i = blockIdx.x * blockDim.x + threadIdx.x; i < n4; i += stride) {
    float4 v = reinterpret_cast<const float4*>(in)[i];
    ushort4 o;
    o.x = f2bf(v.x); o.y = f2bf(v.y); o.z = f2bf(v.z); o.w = f2bf(v.w);
    reinterpret_cast<ushort4*>(out)[i] = o;
  }
}

// ============================================================================
// Ring-3 pipelined GEMM:  C = A(4096 x 2048) * B(N x 2048)^T + bias.
// 512 threads = 8 waves (2 m-groups x 4 n-groups), wave tile (BM/2)x(BN/4).
// K chunked by 32; LDS ring of 3 chunk-slots per operand; per iteration:
//   STAGE(c+2) -> ds_read frags(c) -> 32 MFMA -> vmcnt(LPC) -> s_barrier
// Loads for chunk c+2 stay in flight across two barriers (T4 counted vmcnt).
// Slot (c+2)%3 last held chunk c-1, dead since the previous barrier -> no race.
//
// LDS chunk layout (packed-pair, conflict-free for b128 frag reads AND linear
// for global_load_lds): rows m=2r,2r+1 share a 128B line; byte within line =
// (((m&1)<<6)|kbyte) ^ ((m&7)<<4). Inverse swizzle applied to global source.
// EPI=0: QKV scatter epilogue (bf16).  EPI=1: fp32 row-major C.
// ============================================================================
template<int BM, int BN, int EPI>
__global__ __launch_bounds__(512, 2) void gemm_p3(
    const unsigned short* __restrict__ A, const unsigned short* __restrict__ Bw,
    const float* __restrict__ bias, int N,
    unsigned short* __restrict__ q_out, unsigned short* __restrict__ k_out,
    unsigned short* __restrict__ vt_out, float* __restrict__ c_out)
{
  constexpr int KB2   = 2 * KDIM;       // global row stride in bytes
  constexpr int NCH   = KDIM / 32;      // 64 k-chunks
  constexpr int ABYT  = BM * 64;        // bytes per A chunk (BM rows x 32 k x 2B)
  constexpr int BBYT  = BN * 64;
  constexpr int LPA   = BM / 128;       // gload_lds per thread for A chunk
  constexpr int LPB   = BN / 128;
  constexpr int LPC   = LPA + LPB;
  constexpr int M_SUB = BM / 32;        // per-wave m subtiles (wave rows = BM/2)
  constexpr int N_SUB = BN / 64;        // per-wave n subtiles (wave cols = BN/4)
  constexpr int MBC   = 4096 / BM;

  __shared__ char lsA[3 * ABYT];
  __shared__ char lsB[3 * BBYT];

  const int tid = threadIdx.x, l = tid & 63, w = tid >> 6;
  const int wr = w >> 2, wc = w & 3;
  const int row16 = l & 15, kg = l >> 4;

  // XCD-chunked block swizzle (nwg % 8 == 0 for both launches)
  const int nwg = gridDim.x;
  const int bid = blockIdx.x;
  const int swz = (bid & 7) * (nwg >> 3) + (bid >> 3);
  const int bm = (swz % MBC) * BM, bn = (swz / MBC) * BN;

  const char* Ag = (const char*)A + (size_t)bm * KB2;
  const char* Bg = (const char*)Bw + (size_t)bn * KB2;

  f32x4 acc[M_SUB][N_SUB] = {};

  // stage chunk cc into ring slot sl. Linear LDS dest (wave-uniform base),
  // inverse-swizzled per-lane global source.
#define STAGE(cc, sl) do {                                                     \
    _Pragma("unroll")                                                          \
    for (int p = 0; p < LPA; ++p) {                                            \
      const int ob = (p * 8 + w) << 10;                                        \
      const int o = ob + l * 16;                                               \
      const int m2 = o >> 7, sw = o & 127;                                     \
      const int t = sw ^ (((m2 << 1) & 7) << 4);                               \
      const int odd = (t >> 6) & 1;                                            \
      const int m = (m2 << 1) | odd;                                           \
      const int kb = (t ^ (odd << 4)) & 63;                                    \
      gload_lds16(Ag + (size_t)m * KB2 + (cc) * 64 + kb,                       \
                  lsA + (sl) * ABYT + ob);                                     \
    }                                                                          \
    _Pragma("unroll")                                                          \
    for (int p = 0; p < LPB; ++p) {                                            \
      const int ob = (p * 8 + w) << 10;                                        \
      const int o = ob + l * 16;                                               \
      const int m2 = o >> 7, sw = o & 127;                                     \
      const int t = sw ^ (((m2 << 1) & 7) << 4);                               \
      const int odd = (t >> 6) & 1;                                            \
      const int m = (m2 << 1) | odd;                                           \
      const int kb = (t ^ (odd << 4)) & 63;                                    \
      gload_lds16(Bg + (size_t)m * KB2 + (cc) * 64 + kb,                       \
                  lsB + (sl) * BBYT + ob);                                     \
    } } while (0)

  STAGE(0, 0);
  STAGE(1, 1);
  waitvm<LPC>();                         // chunk 0 landed; chunk 1 in flight
  asm volatile("s_barrier" ::: "memory");

  int sl = 0;
  for (int c = 0; c < NCH; ++c) {
    int cs = c + 2; if (cs >= NCH) cs -= NCH;   // tail: dummy re-stage (slot is dead)
    int s2 = sl + 2; if (s2 >= 3) s2 -= 3;
    STAGE(cs, s2);

    const char* Ac = lsA + sl * ABYT;
    const char* Bc = lsB + sl * BBYT;
    bf16x8 af[M_SUB], bf[N_SUB];
    #pragma unroll
    for (int i = 0; i < M_SUB; ++i) {
      const int m = wr * (BM / 2) + i * 16 + row16;
      af[i] = *(const bf16x8*)(Ac + (m >> 1) * 128 +
              ((((m & 1) << 6) | (kg << 4)) ^ ((m & 7) << 4)));
    }
    #pragma unroll
    for (int j = 0; j < N_SUB; ++j) {
      const int n = wc * (BN / 4) + j * 16 + row16;
      bf[j] = *(const bf16x8*)(Bc + (n >> 1) * 128 +
              ((((n & 1) << 6) | (kg << 4)) ^ ((n & 7) << 4)));
    }

    __builtin_amdgcn_s_setprio(1);
    #pragma unroll
    for (int i = 0; i < M_SUB; ++i)
      #pragma unroll
      for (int j = 0; j < N_SUB; ++j)
        acc[i][j] = mfma16(af[i], bf[j], acc[i][j]);
    __builtin_amdgcn_s_setprio(0);

    waitvm<LPC>();                       // chunk c+1 landed; c+2 stays in flight
    __builtin_amdgcn_sched_barrier(0);
    asm volatile("s_barrier" ::: "memory");

    sl = sl + 1; if (sl == 3) sl = 0;
  }
#undef STAGE
  waitvm<0>();   // drain dummy-stage LDS-DMA before this block's LDS is released

  // C/D layout: col = lane&15, row = (lane>>4)*4 + reg  [m89]
  #pragma unroll
  for (int i = 0; i < M_SUB; ++i) {
    const int row = bm + wr * (BM / 2) + i * 16 + kg * 4;
    #pragma unroll
    for (int j = 0; j < N_SUB; ++j) {
      const int col = bn + wc * (BN / 4) + j * 16 + row16;
      const float bv = bias[col];
      if (EPI == 1) {
        #pragma unroll
        for (int r = 0; r < 4; ++r)
          c_out[(size_t)(row + r) * N + col] = acc[i][j][r] + bv;
      } else {
        const int sec = col >> 11;           // 0=Q 1=K 2=V
        const int within = col & 2047;
        const int head = within >> 7, d = within & 127;
        #pragma unroll
        for (int r = 0; r < 4; ++r) {
          const int rr = row + r;
          const int b = rr >> 11, s = rr & 2047;
          const int bh = b * NHEAD + head;
          const float v = acc[i][j][r] + bv;
          if (sec == 0)
            q_out[((size_t)bh * S_LEN + s) * DHEAD + d] = f2bf(v * QSCALE_L2E);
          else if (sec == 1)
            k_out[((size_t)bh * S_LEN + s) * DHEAD + d] = f2bf(v);
          else  // V stored transposed per head: Vt[bh][d][s]
            vt_out[((size_t)bh * DHEAD + d) * S_LEN + s] = f2bf(v);
        }
      }
    }
  }
}

// Causal flash attention: swapped QK^T, 32 q-rows/wave, 2-phase dbuf pipeline.
// Grid: (16 q-tiles of 128 rows, 32 bh). Block: 4 waves.
__global__ __launch_bounds__(256, 2) void attn_fwd(
    const unsigned short* __restrict__ Q, const unsigned short* __restrict__ Kk,
    const unsigned short* __restrict__ Vt, unsigned short* __restrict__ O)
{
  __shared__ char lsK[2][64 * 256];    // dbuf [64 kv][128 d] bf16, XOR-swizzled
  __shared__ char lsV[2][128 * 128];   // dbuf [128 d][64 kv] bf16, XOR-swizzled
  __shared__ char lsP[4][32 * 128];    // per-wave [32 q][64 kv] bf16, XOR-swizzled
  const int tid = threadIdx.x, l = tid & 63, w = tid >> 6;
  const int row16 = l & 15, kg = l >> 4;
  const int qb = (blockIdx.y < 16) ? (15 - (int)blockIdx.x) : (int)blockIdx.x;
  const int bh = blockIdx.y;
  const int bidx = bh >> 4, head = bh & 15;

  const char* Qh = (const char*)(Q  + (size_t)bh * S_LEN * DHEAD);
  const char* Kh = (const char*)(Kk + (size_t)bh * S_LEN * DHEAD);
  const char* Vh = (const char*)(Vt + (size_t)bh * DHEAD * S_LEN);

  const int q0w = qb * 128 + w * 32;   // this wave's first q row

  bf16x8 qf[2][4];
  #pragma unroll
  for (int qs = 0; qs < 2; ++qs)
    #pragma unroll
    for (int t = 0; t < 4; ++t)
      qf[qs][t] = *(const bf16x8*)(Qh + ((size_t)(q0w + qs * 16 + row16) * DHEAD + t * 32 + kg * 8) * 2);

  float m[2]  = {-1e30f, -1e30f};
  float ls[2] = {0.f, 0.f};
  f32x4 oacc[2][8] = {};

  const int last = 2 * qb + 1;

#define STAGE(buf, kt_) do {                                                     \
    _Pragma("unroll")                                                            \
    for (int c = 0; c < 4; ++c) {                                                \
      const int o = c * 4096 + tid * 16;                                         \
      const int rk = o >> 8, cbk = (o & 255) ^ ((rk & 7) << 4);                  \
      gload_lds16(Kh + (size_t)((kt_) * 64 + rk) * 256 + cbk,                    \
                  lsK[buf] + c * 4096 + (w << 10));                              \
      const int dv = o >> 7, cbv = (o & 127) ^ ((dv & 7) << 4);                  \
      gload_lds16(Vh + (size_t)dv * 4096 + (size_t)(kt_) * 128 + cbv,            \
                  lsV[buf] + c * 4096 + (w << 10));                              \
    } } while (0)

  STAGE(0, 0);
  __syncthreads();

  int cur = 0;
  for (int kt = 0; ; ++kt) {
    if (kt < last) STAGE(cur ^ 1, kt + 1);   // prefetch next tile

    if (kt * 64 <= q0w + 31) {
      const char* Kc = lsK[cur];
      const char* Vc = lsV[cur];
      char* Pl = lsP[w];

      f32x4 sc[4][2] = {};
      #pragma unroll
      for (int j = 0; j < 4; ++j) {
        const int krow = j * 16 + row16;
        const int sw = (krow & 7) << 4;
        bf16x8 kf[4];
        #pragma unroll
        for (int t = 0; t < 4; ++t)
          kf[t] = *(const bf16x8*)(Kc + krow * 256 + ((t * 64 + kg * 16) ^ sw));
        #pragma unroll
        for (int t = 0; t < 4; ++t) {
          sc[j][0] = mfma16(kf[t], qf[0][t], sc[j][0]);
          sc[j][1] = mfma16(kf[t], qf[1][t], sc[j][1]);
        }
      }

      if (kt >= 2 * qb) {
        #pragma unroll
        for (int j = 0; j < 4; ++j) {
          const int kvb = kt * 64 + j * 16 + kg * 4;
          #pragma unroll
          for (int qs = 0; qs < 2; ++qs) {
            const int qq = q0w + qs * 16 + row16;
            #pragma unroll
            for (int r = 0; r < 4; ++r)
              if (kvb + r > qq) sc[j][qs][r] = -1e30f;
          }
        }
      }

      float pm[2], al[2] = {1.f, 1.f};
      #pragma unroll
      for (int qs = 0; qs < 2; ++qs) {
        float mx = fmaxf(fmaxf(hmax4(sc[0][qs]), hmax4(sc[1][qs])),
                         fmaxf(hmax4(sc[2][qs]), hmax4(sc[3][qs])));
        mx = fmaxf(mx, __shfl_xor(mx, 16, 64));
        mx = fmaxf(mx, __shfl_xor(mx, 32, 64));
        pm[qs] = mx;
      }
      const bool need = (pm[0] > m[0] + 8.f) || (pm[1] > m[1] + 8.f);
      if (__any(need)) {
        const float n0 = fmaxf(m[0], pm[0]), n1 = fmaxf(m[1], pm[1]);
        al[0] = exp2f(m[0] - n0); al[1] = exp2f(m[1] - n1);
        m[0] = n0; m[1] = n1;
        float aq[2][4];
        #pragma unroll
        for (int qs2 = 0; qs2 < 2; ++qs2)
          #pragma unroll
          for (int r = 0; r < 4; ++r)
            aq[qs2][r] = __shfl(al[qs2], kg * 4 + r, 64);
        #pragma unroll
        for (int qs2 = 0; qs2 < 2; ++qs2)
          #pragma unroll
          for (int dt = 0; dt < 8; ++dt)
            #pragma unroll
            for (int r = 0; r < 4; ++r)
              oacc[qs2][dt][r] *= aq[qs2][r];
      }

      #pragma unroll
      for (int qs = 0; qs < 2; ++qs) {
        const int q = qs * 16 + row16;
        const int psw = (q & 7) << 4;
        float ps = 0.f;
        #pragma unroll
        for (int j = 0; j < 4; ++j) {
          const float p0 = exp2f(sc[j][qs][0] - m[qs]);
          const float p1 = exp2f(sc[j][qs][1] - m[qs]);
          const float p2 = exp2f(sc[j][qs][2] - m[qs]);
          const float p3 = exp2f(sc[j][qs][3] - m[qs]);
          ps += (p0 + p1) + (p2 + p3);
          uint2 pw; pw.x = pkbf(p0, p1); pw.y = pkbf(p2, p3);
          *(uint2*)(Pl + q * 128 + ((j * 32 + kg * 8) ^ psw)) = pw;
        }
        ps += __shfl_xor(ps, 16, 64);
        ps += __shfl_xor(ps, 32, 64);
        ls[qs] = ls[qs] * al[qs] + ps;
      }

      bf16x8 pa[2][2];
      #pragma unroll
      for (int qs2 = 0; qs2 < 2; ++qs2) {
        const int q = qs2 * 16 + row16;
        #pragma unroll
        for (int ks = 0; ks < 2; ++ks)
          pa[qs2][ks] = *(const bf16x8*)(Pl + q * 128 + ((ks * 64 + kg * 16) ^ ((q & 7) << 4)));
      }
      #pragma unroll
      for (int dt = 0; dt < 8; ++dt) {
        const int drow = dt * 16 + row16;
        const int vsw = (drow & 7) << 4;
        bf16x8 v0 = *(const bf16x8*)(Vc + drow * 128 + ((kg * 16) ^ vsw));
        bf16x8 v1 = *(const bf16x8*)(Vc + drow * 128 + ((64 + kg * 16) ^ vsw));
        oacc[0][dt] = mfma16(pa[0][0], v0, oacc[0][dt]);
        oacc[0][dt] = mfma16(pa[0][1], v1, oacc[0][dt]);
        oacc[1][dt] = mfma16(pa[1][0], v0, oacc[1][dt]);
        oacc[1][dt] = mfma16(pa[1][1], v1, oacc[1][dt]);
      }
    }

    __syncthreads();
    if (kt == last) break;
    cur ^= 1;
  }
#undef STAGE

  #pragma unroll
  for (int qs2 = 0; qs2 < 2; ++qs2) {
    #pragma unroll
    for (int r = 0; r < 4; ++r) {
      const float lr = __shfl(ls[qs2], kg * 4 + r, 64);
      const float inv = 1.0f / lr;
      const int q = q0w + qs2 * 16 + kg * 4 + r;
      const size_t orow = (size_t)(bidx * S_LEN + q) * HID + (size_t)head * DHEAD;
      #pragma unroll
      for (int dt = 0; dt < 8; ++dt)
        O[orow + dt * 16 + row16] = f2bf(oacc[qs2][dt][r] * inv);
    }
  }
}

extern "C" void kernel_launch(void* const* d_in, const int* in_sizes, int n_in,
                              void* d_out, int out_size, void* d_ws, size_t ws_size,
                              hipStream_t stream) {
  const float* x    = (const float*)d_in[0];
  const float* Wqkv = (const float*)d_in[1];
  const float* bqkv = (const float*)d_in[2];
  const float* Wout = (const float*)d_in[3];
  const float* bout = (const float*)d_in[4];
  float* out = (float*)d_out;

  if (ws_size < 100663296) return;  // insufficient scratch -> clean validation fail
  char* ws = (char*)d_ws;
  unsigned short* Qb    = (unsigned short*)(ws);
  unsigned short* Kb    = (unsigned short*)(ws + 16777216);
  unsigned short* Vtb   = (unsigned short*)(ws + 2 * 16777216);
  unsigned short* xb    = (unsigned short*)(ws + 3 * 16777216);
  unsigned short* Ob    = xb;  // alias: xb dead after QKV GEMM, Ob written after
  unsigned short* Wqkvb = (unsigned short*)(ws + 4 * 16777216);
  unsigned short* Woutb = (unsigned short*)(ws + 4 * 16777216 + 25165824);

  cvt_bf16<<<2048, 256, 0, stream>>>(x,    xb,    4096 * 2048);
  cvt_bf16<<<2048, 256, 0, stream>>>(Wqkv, Wqkvb, 6144 * 2048);
  cvt_bf16<<<1024, 256, 0, stream>>>(Wout, Woutb, 2048 * 2048);

  // QKV: M=4096, N=6144, 256x256 tiles -> 16x24 = 384 blocks
  gemm_p3<256, 256, 0><<<384, 512, 0, stream>>>(xb, Wqkvb, bqkv, 6144,
                                                Qb, Kb, Vtb, nullptr);
  attn_fwd<<<dim3(16, 32), 256, 0, stream>>>(Qb, Kb, Vtb, Ob);
  // OUT: M=4096, N=2048, 128x256 tiles -> 32x8 = 256 blocks (one full round)
  gemm_p3<128, 256, 1><<<256, 512, 0, stream>>>(Ob, Woutb, bout, 2048,
                                                nullptr, nullptr, nullptr, out);
}

// Round 4
// 317.359 us; speedup vs baseline: 1.2156x; 1.2156x over previous
//
#include <hip/hip_runtime.h>
#include <stdint.h>

// MHA fused: qkv-proj (4-phase counted-vmcnt bf16 MFMA GEMM) -> causal flash attn -> out-proj
// B=2, S=2048, H=2048, heads=16, D=128.

using bf16x8 = __attribute__((ext_vector_type(8))) __bf16;
using f32x4  = __attribute__((ext_vector_type(4))) float;

#define S_LEN 2048
#define HID   2048
#define NHEAD 16
#define DHEAD 128
#define KDIM  2048
// 1/sqrt(128) * log2(e): attention softmax runs in exp2 domain
#define QSCALE_L2E (0.08838834764831845f * 1.4426950408889634f)

__device__ __forceinline__ unsigned short f2bf(float f) {
  union { float f; unsigned int u; } c; c.f = f;
  unsigned int u = c.u;
  return (unsigned short)((u + 0x7FFFu + ((u >> 16) & 1u)) >> 16);  // RNE
}

__device__ __forceinline__ unsigned int pkbf(float a, float b) {
  union { __bf16 h[2]; unsigned int u; } x;
  x.h[0] = (__bf16)a; x.h[1] = (__bf16)b;
  return x.u;
}

__device__ __forceinline__ void gload_lds16(const void* g, void* l) {
  __builtin_amdgcn_global_load_lds(
      (const __attribute__((address_space(1))) unsigned int*)g,
      (__attribute__((address_space(3))) unsigned int*)l, 16, 0, 0);
}

__device__ __forceinline__ f32x4 mfma16(bf16x8 a, bf16x8 b, f32x4 c) {
  return __builtin_amdgcn_mfma_f32_16x16x32_bf16(a, b, c, 0, 0, 0);
}

__device__ __forceinline__ float hmax4(f32x4 v) {
  return fmaxf(fmaxf(v[0], v[1]), fmaxf(v[2], v[3]));
}

__global__ void cvt_bf16(const float* __restrict__ in, unsigned short* __restrict__ out, int n) {
  const int n4 = n >> 2;
  const int stride = gridDim.x * blockDim.x;
  for (int i = blockIdx.x * blockDim.x + threadIdx.x; i < n4; i += stride) {
    float4 v = reinterpret_cast<const float4*>(in)[i];
    ushort4 o;
    o.x = f2bf(v.x); o.y = f2bf(v.y); o.z = f2bf(v.z); o.w = f2bf(v.w);
    reinterpret_cast<ushort4*>(out)[i] = o;
  }
}

// ============================================================================
// QKV GEMM, 4-phase counted-vmcnt schedule (m201-class).
// C(4096 x 6144) = A * Wqkv^T + b, scatter epilogue to Q/K/Vt.
// 256x256 tile, BK=64, 512 thr = 8 waves (2m x 4n), wave tile 128x64.
// LDS 128 KB: lsA[2][256][64bf16], lsB same; swizzle byte^=((row&7)<<4)
// (round-2 proven: 0 bank conflicts on both gload_lds-linear and ds_read_b128).
//
// Per K-tile: 4 phases x 16 MFMA. Quarters (16 KB, 2 loads/thread):
//   A0: rows (r&127)<64   read ph1 (a-lo)     A1: rows >=64  read ph2 (a-hi)
//   B0: rows (r&63)<32    read ph1 (b-lo)     B1: rows >=32  read ph3 (b-hi)
// Stage into dead buffer: ph1->A0', ph2->B0', ph3->A1', ph4->B1'.
// vmcnt(4) at ph1/ph2/ph4 ends. Ledger (2 loads/quarter, steady state,
// entering iter t in-flight = [A1(t),B1(t)]):
//  ph1 +A0': 6 out; vmcnt(4) -> A1(t) landed (deadline ph2 read)   ok
//  ph2 +B0': 6 out; vmcnt(4) -> B1(t) landed (deadline ph3 read)   ok
//  ph3 +A1': 6 out; no wait
//  ph4 +B1': 8 out; vmcnt(4) -> A0',B0' landed (deadline next ph1) ok
// Final tile: no stages; vmcnt(2) before a-hi read, vmcnt(0) before b-hi.
// ============================================================================
__global__ __launch_bounds__(512, 2) void gemm_qkv8(
    const unsigned short* __restrict__ A, const unsigned short* __restrict__ Bw,
    const float* __restrict__ bias,
    unsigned short* __restrict__ q_out, unsigned short* __restrict__ k_out,
    unsigned short* __restrict__ vt_out)
{
  __shared__ char lsA[2][32768];
  __shared__ char lsB[2][32768];
  const int tid = threadIdx.x, l = tid & 63, w = tid >> 6;
  const int wr = w >> 2, wc = w & 3;
  const int row16 = l & 15, kg = l >> 4;

  // XCD-chunked swizzle: 384 blocks, 48/XCD; bm fastest -> shared B panels per XCD
  const int bid = blockIdx.x;
  const int swz = (bid & 7) * 48 + (bid >> 3);
  const int bm = (swz & 15) * 256, bn = (swz >> 4) * 256;
  const char* Ag = (const char*)A + (size_t)bm * (KDIM * 2);
  const char* Bg = (const char*)Bw + (size_t)bn * (KDIM * 2);

  f32x4 acc[8][4] = {};

  // bias preload + force completion so loop vmcnt counts stay clean
  float bv[4];
  #pragma unroll
  for (int j = 0; j < 4; ++j) bv[j] = bias[bn + wc * 64 + j * 16 + row16];
  asm volatile("" :: "v"(bv[0]), "v"(bv[1]), "v"(bv[2]), "v"(bv[3]));

#define BAR   asm volatile("s_barrier" ::: "memory")
#define LGKM0 asm volatile("s_waitcnt lgkmcnt(0)" ::: "memory"); __builtin_amdgcn_sched_barrier(0)
#define VM4   asm volatile("s_waitcnt vmcnt(4)" ::: "memory")
#define PRIO1 __builtin_amdgcn_s_setprio(1)
#define PRIO0 __builtin_amdgcn_s_setprio(0)

  // A quarter qa: rows {qa*64..qa*64+63, 128+qa*64..}; linear LDS dest, inv-swz source
#define STAGE_A(buf, k0, qa) do {                                              \
    _Pragma("unroll")                                                          \
    for (int p = 0; p < 2; ++p) {                                              \
      const int o = tid * 16;                                                  \
      const int r = p * 128 + (qa) * 64 + (o >> 7);                            \
      const int cb = (o & 127) ^ ((r & 7) << 4);                               \
      gload_lds16(Ag + (size_t)r * (KDIM * 2) + (k0) * 2 + cb,                 \
                  lsA[buf] + p * 16384 + (qa) * 8192 + o);                     \
    } } while (0)

  // B quarter qb: rows with (r&63) in [qb*32, qb*32+32)
#define STAGE_B(buf, k0, qb) do {                                              \
    _Pragma("unroll")                                                          \
    for (int p = 0; p < 2; ++p) {                                              \
      const int o = tid * 16;                                                  \
      const int blk = o >> 12;                                                 \
      const int r = p * 128 + blk * 64 + (qb) * 32 + ((o >> 7) & 31);          \
      const int cb = (o & 127) ^ ((r & 7) << 4);                               \
      gload_lds16(Bg + (size_t)r * (KDIM * 2) + (k0) * 2 + cb,                 \
                  lsB[buf] + p * 16384 + blk * 8192 + (qb) * 4096 + (o & 4095)); \
    } } while (0)

#define RD_A(dst, i0) do { _Pragma("unroll")                                   \
    for (int i = 0; i < 4; ++i) {                                              \
      const int m = wr * 128 + ((i0) + i) * 16 + row16;                        \
      _Pragma("unroll")                                                        \
      for (int h = 0; h < 2; ++h)                                              \
        dst[i][h] = *(const bf16x8*)(Ac + m * 128 + ((h * 64 + kg * 16) ^ ((m & 7) << 4))); \
    } } while (0)

#define RD_B(dst, j0) do { _Pragma("unroll")                                   \
    for (int j = 0; j < 2; ++j) {                                              \
      const int n = wc * 64 + ((j0) + j) * 16 + row16;                         \
      _Pragma("unroll")                                                        \
      for (int h = 0; h < 2; ++h)                                              \
        dst[j][h] = *(const bf16x8*)(Bc + n * 128 + ((h * 64 + kg * 16) ^ ((n & 7) << 4))); \
    } } while (0)

#define MM(afrag, bfrag, i0, j0) do { _Pragma("unroll")                        \
    for (int i = 0; i < 4; ++i) { _Pragma("unroll")                            \
      for (int j = 0; j < 2; ++j) { _Pragma("unroll")                          \
        for (int h = 0; h < 2; ++h)                                            \
          acc[(i0) + i][(j0) + j] = mfma16(afrag[i][h], bfrag[j][h], acc[(i0) + i][(j0) + j]); \
    } } } while (0)

  // prologue: tile 0 fully staged, nothing else in flight
  STAGE_A(0, 0, 0); STAGE_B(0, 0, 0); STAGE_A(0, 0, 1); STAGE_B(0, 0, 1);
  asm volatile("s_waitcnt vmcnt(0)" ::: "memory");
  BAR;

  bf16x8 afl[4][2], afh[4][2], bfl[2][2], bfh[2][2];
  constexpr int NCH = KDIM / 64;   // 32

  #pragma unroll 1
  for (int t = 0; t < NCH - 1; ++t) {
    const int cur = t & 1, nxt = cur ^ 1;
    const char* Ac = lsA[cur];
    const char* Bc = lsB[cur];
    const int k1 = (t + 1) * 64;
    // ---- ph1: a-lo x b-lo
    RD_A(afl, 0); RD_B(bfl, 0);
    STAGE_A(nxt, k1, 0);
    BAR; LGKM0;
    PRIO1; MM(afl, bfl, 0, 0); PRIO0;
    VM4; BAR;
    // ---- ph2: a-hi x b-lo
    RD_A(afh, 4);
    STAGE_B(nxt, k1, 0);
    BAR; LGKM0;
    PRIO1; MM(afh, bfl, 4, 0); PRIO0;
    VM4; BAR;
    // ---- ph3: a-lo x b-hi (afl held since ph1)
    RD_B(bfh, 2);
    STAGE_A(nxt, k1, 1);
    BAR; LGKM0;
    PRIO1; MM(afl, bfh, 0, 2); PRIO0;
    BAR;
    // ---- ph4: a-hi x b-hi (afh, bfh held)
    STAGE_B(nxt, k1, 1);
    BAR;
    PRIO1; MM(afh, bfh, 4, 2); PRIO0;
    VM4; BAR;
  }
  { // final K-tile: drain 4 -> 2 -> 0
    const char* Ac = lsA[(NCH - 1) & 1];
    const char* Bc = lsB[(NCH - 1) & 1];
    RD_A(afl, 0); RD_B(bfl, 0);
    MM(afl, bfl, 0, 0);
    asm volatile("s_waitcnt vmcnt(2)" ::: "memory");   // A1 landed
    RD_A(afh, 4);
    MM(afh, bfl, 4, 0);
    asm volatile("s_waitcnt vmcnt(0)" ::: "memory");   // B1 landed
    RD_B(bfh, 2);
    MM(afl, bfh, 0, 2);
    MM(afh, bfh, 4, 2);
  }
#undef STAGE_A
#undef STAGE_B
#undef RD_A
#undef RD_B
#undef MM
#undef BAR
#undef LGKM0
#undef VM4
#undef PRIO1
#undef PRIO0

  // scatter epilogue: C/D layout col = lane&15, row = (lane>>4)*4 + reg
  #pragma unroll
  for (int i = 0; i < 8; ++i) {
    const int row = bm + wr * 128 + i * 16 + kg * 4;
    #pragma unroll
    for (int j = 0; j < 4; ++j) {
      const int col = bn + wc * 64 + j * 16 + row16;
      const int sec = col >> 11;           // 0=Q 1=K 2=V
      const int within = col & 2047;
      const int head = within >> 7, d = within & 127;
      #pragma unroll
      for (int r = 0; r < 4; ++r) {
        const int rr = row + r;
        const int b = rr >> 11, s = rr & 2047;
        const int bh = b * NHEAD + head;
        const float v = acc[i][j][r] + bv[j];
        if (sec == 0)
          q_out[((size_t)bh * S_LEN + s) * DHEAD + d] = f2bf(v * QSCALE_L2E);
        else if (sec == 1)
          k_out[((size_t)bh * S_LEN + s) * DHEAD + d] = f2bf(v);
        else  // V stored transposed per head: Vt[bh][d][s]
          vt_out[((size_t)bh * DHEAD + d) * S_LEN + s] = f2bf(v);
      }
    }
  }
}

// Out-projection: round-2 proven 128x128-tile GEMM, fp32 epilogue.
__global__ __launch_bounds__(256) void gemm_out(
    const unsigned short* __restrict__ A, const unsigned short* __restrict__ Bw,
    const float* __restrict__ bias, float* __restrict__ c_out)
{
  constexpr int K = KDIM, N = HID;
  __shared__ char lsA[128 * 128];
  __shared__ char lsB[128 * 128];
  const int tid = threadIdx.x;
  const int l = tid & 63, w = tid >> 6;
  const int wr = w >> 1, wc = w & 1;
  const int bm = blockIdx.x * 128, bn = blockIdx.y * 128;
  const int row16 = l & 15, kg = l >> 4;

  f32x4 acc[4][4] = {};

  for (int k0 = 0; k0 < K; k0 += 64) {
    #pragma unroll
    for (int c = 0; c < 4; ++c) {
      const int o = c * 4096 + tid * 16;
      const int r = o >> 7;
      const int cb = (o & 127) ^ ((r & 7) << 4);
      gload_lds16((const char*)A + ((size_t)(bm + r) * K + k0) * 2 + cb,
                  lsA + c * 4096 + (w << 10));
      gload_lds16((const char*)Bw + ((size_t)(bn + r) * K + k0) * 2 + cb,
                  lsB + c * 4096 + (w << 10));
    }
    __syncthreads();

    #pragma unroll
    for (int h = 0; h < 2; ++h) {
      bf16x8 af[4], bfr[4];
      #pragma unroll
      for (int i = 0; i < 4; ++i) {
        const int ra = wr * 64 + i * 16 + row16;
        af[i]  = *(const bf16x8*)(lsA + ra * 128 + ((h * 64 + kg * 16) ^ ((ra & 7) << 4)));
        const int rb = wc * 64 + i * 16 + row16;
        bfr[i] = *(const bf16x8*)(lsB + rb * 128 + ((h * 64 + kg * 16) ^ ((rb & 7) << 4)));
      }
      #pragma unroll
      for (int i = 0; i < 4; ++i)
        #pragma unroll
        for (int j = 0; j < 4; ++j)
          acc[i][j] = mfma16(af[i], bfr[j], acc[i][j]);
    }
    __syncthreads();
  }

  #pragma unroll
  for (int i = 0; i < 4; ++i) {
    const int row = bm + wr * 64 + i * 16 + kg * 4;
    #pragma unroll
    for (int j = 0; j < 4; ++j) {
      const int col = bn + wc * 64 + j * 16 + row16;
      const float bvj = bias[col];
      #pragma unroll
      for (int r = 0; r < 4; ++r)
        c_out[(size_t)(row + r) * N + col] = acc[i][j][r] + bvj;
    }
  }
}

// Causal flash attention: swapped QK^T, 32 q-rows/wave, 2-phase dbuf pipeline.
__global__ __launch_bounds__(256, 2) void attn_fwd(
    const unsigned short* __restrict__ Q, const unsigned short* __restrict__ Kk,
    const unsigned short* __restrict__ Vt, unsigned short* __restrict__ O)
{
  __shared__ char lsK[2][64 * 256];
  __shared__ char lsV[2][128 * 128];
  __shared__ char lsP[4][32 * 128];
  const int tid = threadIdx.x, l = tid & 63, w = tid >> 6;
  const int row16 = l & 15, kg = l >> 4;
  const int qb = (blockIdx.y < 16) ? (15 - (int)blockIdx.x) : (int)blockIdx.x;
  const int bh = blockIdx.y;
  const int bidx = bh >> 4, head = bh & 15;

  const char* Qh = (const char*)(Q  + (size_t)bh * S_LEN * DHEAD);
  const char* Kh = (const char*)(Kk + (size_t)bh * S_LEN * DHEAD);
  const char* Vh = (const char*)(Vt + (size_t)bh * DHEAD * S_LEN);

  const int q0w = qb * 128 + w * 32;

  bf16x8 qf[2][4];
  #pragma unroll
  for (int qs = 0; qs < 2; ++qs)
    #pragma unroll
    for (int t = 0; t < 4; ++t)
      qf[qs][t] = *(const bf16x8*)(Qh + ((size_t)(q0w + qs * 16 + row16) * DHEAD + t * 32 + kg * 8) * 2);

  float m[2]  = {-1e30f, -1e30f};
  float ls[2] = {0.f, 0.f};
  f32x4 oacc[2][8] = {};

  const int last = 2 * qb + 1;

#define STAGE(buf, kt_) do {                                                     \
    _Pragma("unroll")                                                            \
    for (int c = 0; c < 4; ++c) {                                                \
      const int o = c * 4096 + tid * 16;                                         \
      const int rk = o >> 8, cbk = (o & 255) ^ ((rk & 7) << 4);                  \
      gload_lds16(Kh + (size_t)((kt_) * 64 + rk) * 256 + cbk,                    \
                  lsK[buf] + c * 4096 + (w << 10));                              \
      const int dv = o >> 7, cbv = (o & 127) ^ ((dv & 7) << 4);                  \
      gload_lds16(Vh + (size_t)dv * 4096 + (size_t)(kt_) * 128 + cbv,            \
                  lsV[buf] + c * 4096 + (w << 10));                              \
    } } while (0)

  STAGE(0, 0);
  __syncthreads();

  int cur = 0;
  for (int kt = 0; ; ++kt) {
    if (kt < last) STAGE(cur ^ 1, kt + 1);

    if (kt * 64 <= q0w + 31) {
      const char* Kc = lsK[cur];
      const char* Vc = lsV[cur];
      char* Pl = lsP[w];

      f32x4 sc[4][2] = {};
      #pragma unroll
      for (int j = 0; j < 4; ++j) {
        const int krow = j * 16 + row16;
        const int sw = (krow & 7) << 4;
        bf16x8 kf[4];
        #pragma unroll
        for (int t = 0; t < 4; ++t)
          kf[t] = *(const bf16x8*)(Kc + krow * 256 + ((t * 64 + kg * 16) ^ sw));
        #pragma unroll
        for (int t = 0; t < 4; ++t) {
          sc[j][0] = mfma16(kf[t], qf[0][t], sc[j][0]);
          sc[j][1] = mfma16(kf[t], qf[1][t], sc[j][1]);
        }
      }

      if (kt >= 2 * qb) {
        #pragma unroll
        for (int j = 0; j < 4; ++j) {
          const int kvb = kt * 64 + j * 16 + kg * 4;
          #pragma unroll
          for (int qs = 0; qs < 2; ++qs) {
            const int qq = q0w + qs * 16 + row16;
            #pragma unroll
            for (int r = 0; r < 4; ++r)
              if (kvb + r > qq) sc[j][qs][r] = -1e30f;
          }
        }
      }

      float pm[2], al[2] = {1.f, 1.f};
      #pragma unroll
      for (int qs = 0; qs < 2; ++qs) {
        float mx = fmaxf(fmaxf(hmax4(sc[0][qs]), hmax4(sc[1][qs])),
                         fmaxf(hmax4(sc[2][qs]), hmax4(sc[3][qs])));
        mx = fmaxf(mx, __shfl_xor(mx, 16, 64));
        mx = fmaxf(mx, __shfl_xor(mx, 32, 64));
        pm[qs] = mx;
      }
      const bool need = (pm[0] > m[0] + 8.f) || (pm[1] > m[1] + 8.f);
      if (__any(need)) {
        const float n0 = fmaxf(m[0], pm[0]), n1 = fmaxf(m[1], pm[1]);
        al[0] = exp2f(m[0] - n0); al[1] = exp2f(m[1] - n1);
        m[0] = n0; m[1] = n1;
        float aq[2][4];
        #pragma unroll
        for (int qs2 = 0; qs2 < 2; ++qs2)
          #pragma unroll
          for (int r = 0; r < 4; ++r)
            aq[qs2][r] = __shfl(al[qs2], kg * 4 + r, 64);
        #pragma unroll
        for (int qs2 = 0; qs2 < 2; ++qs2)
          #pragma unroll
          for (int dt = 0; dt < 8; ++dt)
            #pragma unroll
            for (int r = 0; r < 4; ++r)
              oacc[qs2][dt][r] *= aq[qs2][r];
      }

      #pragma unroll
      for (int qs = 0; qs < 2; ++qs) {
        const int q = qs * 16 + row16;
        const int psw = (q & 7) << 4;
        float ps = 0.f;
        #pragma unroll
        for (int j = 0; j < 4; ++j) {
          const float p0 = exp2f(sc[j][qs][0] - m[qs]);
          const float p1 = exp2f(sc[j][qs][1] - m[qs]);
          const float p2 = exp2f(sc[j][qs][2] - m[qs]);
          const float p3 = exp2f(sc[j][qs][3] - m[qs]);
          ps += (p0 + p1) + (p2 + p3);
          uint2 pw; pw.x = pkbf(p0, p1); pw.y = pkbf(p2, p3);
          *(uint2*)(Pl + q * 128 + ((j * 32 + kg * 8) ^ psw)) = pw;
        }
        ps += __shfl_xor(ps, 16, 64);
        ps += __shfl_xor(ps, 32, 64);
        ls[qs] = ls[qs] * al[qs] + ps;
      }

      bf16x8 pa[2][2];
      #pragma unroll
      for (int qs2 = 0; qs2 < 2; ++qs2) {
        const int q = qs2 * 16 + row16;
        #pragma unroll
        for (int ks = 0; ks < 2; ++ks)
          pa[qs2][ks] = *(const bf16x8*)(Pl + q * 128 + ((ks * 64 + kg * 16) ^ ((q & 7) << 4)));
      }
      #pragma unroll
      for (int dt = 0; dt < 8; ++dt) {
        const int drow = dt * 16 + row16;
        const int vsw = (drow & 7) << 4;
        bf16x8 v0 = *(const bf16x8*)(Vc + drow * 128 + ((kg * 16) ^ vsw));
        bf16x8 v1 = *(const bf16x8*)(Vc + drow * 128 + ((64 + kg * 16) ^ vsw));
        oacc[0][dt] = mfma16(pa[0][0], v0, oacc[0][dt]);
        oacc[0][dt] = mfma16(pa[0][1], v1, oacc[0][dt]);
        oacc[1][dt] = mfma16(pa[1][0], v0, oacc[1][dt]);
        oacc[1][dt] = mfma16(pa[1][1], v1, oacc[1][dt]);
      }
    }

    __syncthreads();
    if (kt == last) break;
    cur ^= 1;
  }
#undef STAGE

  #pragma unroll
  for (int qs2 = 0; qs2 < 2; ++qs2) {
    #pragma unroll
    for (int r = 0; r < 4; ++r) {
      const float lr = __shfl(ls[qs2], kg * 4 + r, 64);
      const float inv = 1.0f / lr;
      const int q = q0w + qs2 * 16 + kg * 4 + r;
      const size_t orow = (size_t)(bidx * S_LEN + q) * HID + (size_t)head * DHEAD;
      #pragma unroll
      for (int dt = 0; dt < 8; ++dt)
        O[orow + dt * 16 + row16] = f2bf(oacc[qs2][dt][r] * inv);
    }
  }
}

extern "C" void kernel_launch(void* const* d_in, const int* in_sizes, int n_in,
                              void* d_out, int out_size, void* d_ws, size_t ws_size,
                              hipStream_t stream) {
  const float* x    = (const float*)d_in[0];
  const float* Wqkv = (const float*)d_in[1];
  const float* bqkv = (const float*)d_in[2];
  const float* Wout = (const float*)d_in[3];
  const float* bout = (const float*)d_in[4];
  float* out = (float*)d_out;

  if (ws_size < 100663296) return;  // insufficient scratch -> clean validation fail
  char* ws = (char*)d_ws;
  unsigned short* Qb    = (unsigned short*)(ws);
  unsigned short* Kb    = (unsigned short*)(ws + 16777216);
  unsigned short* Vtb   = (unsigned short*)(ws + 2 * 16777216);
  unsigned short* xb    = (unsigned short*)(ws + 3 * 16777216);
  unsigned short* Ob    = xb;  // alias: xb dead after QKV GEMM, Ob written after
  unsigned short* Wqkvb = (unsigned short*)(ws + 4 * 16777216);
  unsigned short* Woutb = (unsigned short*)(ws + 4 * 16777216 + 25165824);

  cvt_bf16<<<2048, 256, 0, stream>>>(x,    xb,    4096 * 2048);
  cvt_bf16<<<2048, 256, 0, stream>>>(Wqkv, Wqkvb, 6144 * 2048);
  cvt_bf16<<<1024, 256, 0, stream>>>(Wout, Woutb, 2048 * 2048);

  // QKV: 16 x 24 tiles of 256^2 -> 384 blocks
  gemm_qkv8<<<384, 512, 0, stream>>>(xb, Wqkvb, bqkv, Qb, Kb, Vtb);
  attn_fwd<<<dim3(16, 32), 256, 0, stream>>>(Qb, Kb, Vtb, Ob);
  gemm_out<<<dim3(32, 16), 256, 0, stream>>>(Ob, Woutb, bout, out);
}